// Round 2
// baseline (2142.711 us; speedup 1.0000x reference)
//
#include <hip/hip_runtime.h>
#include <cmath>

// Problem constants (fixed by the reference's setup_inputs)
constexpr int kF   = 512;   // features
constexpr int kT   = 9;     // teams
constexpr int kS   = 9;     // slots
constexpr int kNP  = 81;    // T*S
constexpr int kH1  = 32;
constexpr int kH2  = 64;
constexpr int kCF  = 32;            // f-chunk staged in LDS
constexpr int kNCH = kF / kCF;      // 16 chunks
constexpr int kBLK = 320;           // 5 waves
constexpr int kACT = 288;           // active threads in pass A / pass B compute

// Workspace layout (floats) — all rewritten by prep every launch (ws is poisoned)
constexpr int WS_W1P  = 0;                       // [t][f][o]  T*F*H1 = 147456
constexpr int WS_W2P  = WS_W1P + kT * kF * kH1;  // [t][o]     T*H1   = 288
constexpr int WS_MW1P = WS_W2P + kT * kH1;       // [f][o]     F*H2   = 32768
constexpr int WS_MW2P = WS_MW1P + kF * kH2;      // [o]        H2     = 64
constexpr int WS_TOTAL = WS_MW2P + kH2;          // 180576 floats = 706 KB

// Shared memory layout (floats)
constexpr int SM_X     = 0;                  // x chunk [f][t][12]  32*108 = 3456
constexpr int SM_TO    = 3456;               // team_out [t][f]     9*512  = 4608
constexpr int SM_Q     = 8064;               // q [t][12]           108
constexpr int SM_TQ    = 8172;               // 16
constexpr int SM_MS    = 8188;               // 16
constexpr int SM_MW    = 8204;               // 16
constexpr int SM_SCALE = 8220;               // 4
constexpr int SM_FLOATS = 8224;              // 32.9 KB -> 4 blocks/CU
// Overlays (regions dead at time of use):
//  - pass-A fs-reduction partials: [0, 5184)   (x + start of to, both idle)
//  - pass-A score partials:        [0, 648)
//  - master hm partials:           [0, 1728);  hm*w products: [1728, 2304)

__device__ __forceinline__ float pnorm1(float x, float g, float b) {
    float r = fmodf(x, 7.0f);           // matches jnp.mod after sign-adjust
    if (r < 0.0f) r += 7.0f;
    return g * ((r - 3.5f) / 3.5f) + b;
}

// ---------------- prep: fold all apply_rot's into the weight matrices ----------------
__global__ void prep_kernel(const float* __restrict__ W1, const float* __restrict__ ang1,
                            const float* __restrict__ W2, const float* __restrict__ ang2,
                            const float* __restrict__ mW1, const float* __restrict__ mang1,
                            const float* __restrict__ mW2, const float* __restrict__ mang2,
                            float* __restrict__ ws) {
    int i = blockIdx.x * 256 + threadIdx.x;
    // W1p[t][f][o] = (R(ang1[t])^T W1[t])[o][f]  (rotation on first 4 f-dims)
    if (i < kT * kF * kH1) {
        int t = i / (kF * kH1); int r = i - t * (kF * kH1);
        int f = r / kH1;        int o = r - f * kH1;
        float v;
        if (f >= 4) {
            v = W1[(t * kH1 + o) * kF + f];
        } else {
            int p = f >> 1; float a = ang1[t * 2 + p];
            float c = cosf(a), s = sinf(a);
            float w0 = W1[(t * kH1 + o) * kF + 2 * p];
            float w1 = W1[(t * kH1 + o) * kF + 2 * p + 1];
            v = (f & 1) ? (-s * w0 + c * w1) : (c * w0 + s * w1);
        }
        ws[WS_W1P + (t * kF + f) * kH1 + o] = v;
    }
    int j = i - kT * kF * kH1;
    if (j >= 0 && j < kT * kH1) {   // W2p[t][o], rotation on first 4 o-dims
        int t = j / kH1, o = j - (j / kH1) * kH1;
        float v;
        if (o >= 4) {
            v = W2[t * kH1 + o];
        } else {
            int p = o >> 1; float a = ang2[t * 2 + p];
            float c = cosf(a), s = sinf(a);
            float w0 = W2[t * kH1 + 2 * p], w1 = W2[t * kH1 + 2 * p + 1];
            v = (o & 1) ? (-s * w0 + c * w1) : (c * w0 + s * w1);
        }
        ws[WS_W2P + j] = v;
    }
    int k = j - kT * kH1;
    if (k >= 0 && k < kF * kH2) {   // mW1p[f][o], rotation on first 8 f-dims (4 planes)
        int f = k / kH2, o = k - (k / kH2) * kH2;
        float v;
        if (f >= 8) {
            v = mW1[o * kF + f];
        } else {
            int p = f >> 1; float a = mang1[p];
            float c = cosf(a), s = sinf(a);
            float w0 = mW1[o * kF + 2 * p], w1 = mW1[o * kF + 2 * p + 1];
            v = (f & 1) ? (-s * w0 + c * w1) : (c * w0 + s * w1);
        }
        ws[WS_MW1P + f * kH2 + o] = v;
    }
    int m = k - kF * kH2;
    if (m >= 0 && m < kH2) {        // mW2p[o], rotation on first 4 o-dims (2 planes)
        float v;
        if (m >= 4) {
            v = mW2[m];
        } else {
            int p = m >> 1; float a = mang2[p];
            float c = cosf(a), s = sinf(a);
            float w0 = mW2[2 * p], w1 = mW2[2 * p + 1];
            v = (m & 1) ? (-s * w0 + c * w1) : (c * w0 + s * w1);
        }
        ws[WS_MW2P + m] = v;
    }
}

// ---------------- main: one block per batch element b ----------------
__global__ __launch_bounds__(kBLK) void scorer_kernel(
    const float* __restrict__ path,  const float* __restrict__ b1,
    const float* __restrict__ gamma1, const float* __restrict__ beta1,
    const float* __restrict__ b2v,   const float* __restrict__ mb1,
    const float* __restrict__ mgamma, const float* __restrict__ mbeta,
    const float* __restrict__ mb2,   const float* __restrict__ c_comm,
    const float* __restrict__ c_res, const float* __restrict__ c_int,
    const float* __restrict__ ws,    float* __restrict__ out) {
    __shared__ float sm[SM_FLOATS];
    const int tid = threadIdx.x;
    const int b = blockIdx.x;
    const float* W1p  = ws + WS_W1P;
    const float* W2p  = ws + WS_W2P;
    const float* mW1p = ws + WS_MW1P;
    const float* mW2p = ws + WS_MW2P;
    const size_t pbase = (size_t)b * (kF * kNP);

    // ======== Pass A: h1[t][s][o] GEMM, register-tiled ========
    // thread = (fs in [0,4), t in [0,9), og in [0,8)); tile = 9 s x 4 o per thread
    const int fs = tid / 72;
    const int tr = (tid % 72) / 8;
    const int og = tid & 7;
    const bool actA = tid < kACT;
    float acc[kS][4];
    #pragma unroll
    for (int s = 0; s < kS; ++s) { acc[s][0] = 0.f; acc[s][1] = 0.f; acc[s][2] = 0.f; acc[s][3] = 0.f; }

    for (int ch = 0; ch < kNCH; ++ch) {
        __syncthreads();   // previous chunk fully consumed
        const float* gsrc = path + pbase + (size_t)ch * (kCF * kNP);
        for (int i = tid; i < kCF * kNP; i += kBLK) {   // coalesced global read
            float v = gsrc[i];
            int f = i / kNP; int j = i - f * kNP;
            int t2 = j / kS; int s2 = j - t2 * kS;
            sm[SM_X + f * 108 + t2 * 12 + s2] = v;      // padded layout, 16B-aligned rows
        }
        __syncthreads();
        if (actA) {
            #pragma unroll 2
            for (int fi = 0; fi < kCF / 4; ++fi) {      // 8 f per thread per chunk
                int fl = fs * (kCF / 4) + fi;
                int fg = ch * kCF + fl;
                const float4 w = *(const float4*)(W1p + (size_t)(tr * kF + fg) * kH1 + og * 4);
                const float* xp = sm + SM_X + fl * 108 + tr * 12;
                float4 xa = *(const float4*)xp;
                float4 xb = *(const float4*)(xp + 4);
                float  xc = xp[8];
                float xs[9] = {xa.x, xa.y, xa.z, xa.w, xb.x, xb.y, xb.z, xb.w, xc};
                #pragma unroll
                for (int s = 0; s < kS; ++s) {
                    acc[s][0] += xs[s] * w.x; acc[s][1] += xs[s] * w.y;
                    acc[s][2] += xs[s] * w.z; acc[s][3] += xs[s] * w.w;
                }
            }
        }
    }

    // fs-reduction (4 partials -> 1), pairwise, region [0, 5184)
    __syncthreads();
    if (actA && fs >= 2) {
        #pragma unroll
        for (int s = 0; s < kS; ++s) {
            float* p = sm + (fs - 2) * 2592 + (tr * kS + s) * kH1 + og * 4;
            p[0] = acc[s][0]; p[1] = acc[s][1]; p[2] = acc[s][2]; p[3] = acc[s][3];
        }
    }
    __syncthreads();
    if (actA && fs < 2) {
        #pragma unroll
        for (int s = 0; s < kS; ++s) {
            const float* p = sm + fs * 2592 + (tr * kS + s) * kH1 + og * 4;
            acc[s][0] += p[0]; acc[s][1] += p[1]; acc[s][2] += p[2]; acc[s][3] += p[3];
        }
    }
    __syncthreads();
    if (actA && fs == 1) {
        #pragma unroll
        for (int s = 0; s < kS; ++s) {
            float* p = sm + (tr * kS + s) * kH1 + og * 4;
            p[0] = acc[s][0]; p[1] = acc[s][1]; p[2] = acc[s][2]; p[3] = acc[s][3];
        }
    }
    __syncthreads();
    float psc[kS];   // partial scores for fs==0 threads
    if (actA && fs == 0) {
        float4 bb = *(const float4*)(b1     + tr * kH1 + og * 4);
        float4 gg = *(const float4*)(gamma1 + tr * kH1 + og * 4);
        float4 be = *(const float4*)(beta1  + tr * kH1 + og * 4);
        float4 w2 = *(const float4*)(W2p    + tr * kH1 + og * 4);
        #pragma unroll
        for (int s = 0; s < kS; ++s) {
            const float* p = sm + (tr * kS + s) * kH1 + og * 4;
            float h0 = acc[s][0] + p[0] + bb.x;
            float h1v = acc[s][1] + p[1] + bb.y;
            float h2 = acc[s][2] + p[2] + bb.z;
            float h3 = acc[s][3] + p[3] + bb.w;
            psc[s] = pnorm1(h0, gg.x, be.x) * w2.x + pnorm1(h1v, gg.y, be.y) * w2.y +
                     pnorm1(h2, gg.z, be.z) * w2.z + pnorm1(h3, gg.w, be.w) * w2.w;
        }
    }
    __syncthreads();   // region [0,648) free now (h1 partials consumed)
    if (actA && fs == 0) {
        #pragma unroll
        for (int s = 0; s < kS; ++s) sm[(tr * kS + s) * 8 + og] = psc[s];
    }
    __syncthreads();
    if (tid < kT) {    // per-team: sum o-partials, softmax over s, q + tq
        float sc[kS]; float mx = -1e30f;
        for (int s = 0; s < kS; ++s) {
            const float* p = sm + (tid * kS + s) * 8;
            float v = p[0] + p[1] + p[2] + p[3] + p[4] + p[5] + p[6] + p[7] + b2v[tid];
            sc[s] = v; mx = fmaxf(mx, v);
        }
        float sum = 0.f;
        for (int s = 0; s < kS; ++s) { sc[s] = expf(sc[s] - mx); sum += sc[s]; }
        float inv = 1.f / sum; float tqv = 0.f;
        for (int s = 0; s < kS; ++s) {
            float qv = sc[s] * inv;
            sm[SM_Q + tid * 12 + s] = qv;
            tqv += qv;
        }
        sm[SM_TQ + tid] = tqv * (1.f / 9.f);
    }
    __syncthreads();

    // ======== Pass B: team_out[t][f] = sum_s x[f][t,s] * q[t][s] ========
    const int tB = tid >> 5, flB = tid & 31;   // tid < 288: t in [0,9), f_local in [0,32)
    float qreg[kS];
    if (tid < kACT) {
        #pragma unroll
        for (int s = 0; s < kS; ++s) qreg[s] = sm[SM_Q + tB * 12 + s];
    }
    for (int ch = 0; ch < kNCH; ++ch) {
        __syncthreads();
        const float* gsrc = path + pbase + (size_t)ch * (kCF * kNP);
        for (int i = tid; i < kCF * kNP; i += kBLK) {   // re-read: L3-served
            float v = gsrc[i];
            int f = i / kNP; int j = i - f * kNP;
            int t2 = j / kS; int s2 = j - t2 * kS;
            sm[SM_X + f * 108 + t2 * 12 + s2] = v;
        }
        __syncthreads();
        if (tid < kACT) {
            const float* xp = sm + SM_X + flB * 108 + tB * 12;
            float v = xp[0]*qreg[0] + xp[1]*qreg[1] + xp[2]*qreg[2] + xp[3]*qreg[3] +
                      xp[4]*qreg[4] + xp[5]*qreg[5] + xp[6]*qreg[6] + xp[7]*qreg[7] +
                      xp[8]*qreg[8];
            sm[SM_TO + tB * kF + ch * kCF + flB] = v;
        }
    }
    __syncthreads();

    // ======== Master: hm = to*mW1p + mb1 -> pnorm -> *mW2p -> softmax over t ========
    const int oM = tid & 63, fsM = tid >> 6;   // tid < 256
    float am[kT];
    #pragma unroll
    for (int t = 0; t < kT; ++t) am[t] = 0.f;
    if (tid < 256) {
        for (int fi = 0; fi < kF / 4; ++fi) {
            int f = fsM * (kF / 4) + fi;
            float w = mW1p[f * kH2 + oM];      // coalesced 256B per wave, L2-hot
            #pragma unroll
            for (int t = 0; t < kT; ++t) am[t] += sm[SM_TO + t * kF + f] * w;
        }
    }
    // reduce over fsM via region [0,1728) (x region, dead); to region untouched
    if (tid < 256 && fsM > 0) {
        #pragma unroll
        for (int t = 0; t < kT; ++t) sm[(fsM - 1) * 576 + t * kH2 + oM] = am[t];
    }
    __syncthreads();
    if (tid < kH2) {   // fsM == 0
        float mb = mb1[tid], g = mgamma[tid], be = mbeta[tid], w2 = mW2p[tid];
        #pragma unroll
        for (int t = 0; t < kT; ++t) {
            float h = am[t] + sm[t * kH2 + tid] + sm[576 + t * kH2 + tid] +
                      sm[1152 + t * kH2 + tid] + mb;
            sm[1728 + t * kH2 + tid] = pnorm1(h, g, be) * w2;
        }
    }
    __syncthreads();
    if (tid < kT) {
        float s = 0.f;
        for (int o = 0; o < kH2; ++o) s += sm[1728 + tid * kH2 + o];
        sm[SM_MS + tid] = s + mb2[0];
    }
    __syncthreads();
    if (tid == 0) {
        float mx = -1e30f;
        for (int t = 0; t < kT; ++t) mx = fmaxf(mx, sm[SM_MS + t]);
        float e[kT]; float sum = 0.f;
        for (int t = 0; t < kT; ++t) { e[t] = expf(sm[SM_MS + t] - mx); sum += e[t]; }
        float inv = 1.f / sum;
        for (int t = 0; t < kT; ++t) sm[SM_MW + t] = e[t] * inv;
        // penalty (tq == 1/9 mathematically; compute anyway from runtime coeffs)
        float mean = 0.f;
        for (int t = 0; t < kT; ++t) mean += sm[SM_TQ + t];
        mean *= (1.f / 9.f);
        float var = 0.f;
        for (int t = 0; t < kT; ++t) { float d = sm[SM_TQ + t] - mean; var += d * d; }
        var *= (1.f / 8.f);   // ddof=1
        float nv = var / (mean * mean + 1e-8f);
        float total = c_comm[0] * (kT * (kT - 1) / 2) + c_res[0] * kT +
                      c_int[0] * kT * (1.f + nv);
        float pen = fminf(total, 0.5f);
        sm[SM_SCALE] = 1.f - pen;
    }
    __syncthreads();
    {
        float mwv[kT];
        #pragma unroll
        for (int t = 0; t < kT; ++t) mwv[t] = sm[SM_MW + t];
        float scl = sm[SM_SCALE];
        for (int f = tid; f < kF; f += kBLK) {
            float v = 0.f;
            #pragma unroll
            for (int t = 0; t < kT; ++t) v += sm[SM_TO + t * kF + f] * mwv[t];
            out[(size_t)b * kF + f] = v * scl;
        }
    }
}

extern "C" void kernel_launch(void* const* d_in, const int* in_sizes, int n_in,
                              void* d_out, int out_size, void* d_ws, size_t ws_size,
                              hipStream_t stream) {
    const float* path   = (const float*)d_in[0];
    const float* W1     = (const float*)d_in[1];
    const float* b1     = (const float*)d_in[2];
    const float* ang1   = (const float*)d_in[3];
    const float* gamma1 = (const float*)d_in[4];
    const float* beta1  = (const float*)d_in[5];
    const float* W2     = (const float*)d_in[6];
    const float* b2     = (const float*)d_in[7];
    const float* ang2   = (const float*)d_in[8];
    const float* mW1    = (const float*)d_in[9];
    const float* mb1    = (const float*)d_in[10];
    const float* mang1  = (const float*)d_in[11];
    const float* mgamma = (const float*)d_in[12];
    const float* mbeta  = (const float*)d_in[13];
    const float* mW2    = (const float*)d_in[14];
    const float* mb2    = (const float*)d_in[15];
    const float* mang2  = (const float*)d_in[16];
    const float* c_comm = (const float*)d_in[17];
    const float* c_res  = (const float*)d_in[18];
    const float* c_int  = (const float*)d_in[19];
    float* ws = (float*)d_ws;
    float* outp = (float*)d_out;

    const int Bn = in_sizes[0] / (kF * kNP);   // 4096

    prep_kernel<<<(WS_TOTAL + 255) / 256, 256, 0, stream>>>(
        W1, ang1, W2, ang2, mW1, mang1, mW2, mang2, ws);
    scorer_kernel<<<Bn, kBLK, 0, stream>>>(
        path, b1, gamma1, beta1, b2, mb1, mgamma, mbeta, mb2,
        c_comm, c_res, c_int, ws, outp);
}